// Round 1
// 1798.927 us; speedup vs baseline: 1.0397x; 1.0397x over previous
//
#include <hip/hip_runtime.h>
#include <hip/hip_bf16.h>

#define T_    256
#define B_    64
#define EMB_  300
#define HID_  256
#define G_    1024   // 4*HID
#define L_    20
#define M_    (T_*B_)  // 16384

// scan decomposition: 32 clusters = 2 dirs x 16 batch-groups; 8 blocks/cluster
#define NCL   32
#define CLB   8
#define BPC   4      // batches per cluster
#define UPB   32     // hidden units per block

typedef float f32x4 __attribute__((ext_vector_type(4)));
typedef unsigned long long u64;

// ---------------------------------------------------------------------------
// Kernel 1: xp[dir][t*B+b][g] = dot(emb[sent[t,b]], Wih_dir[g,:]) + b_dir[g]
// ---------------------------------------------------------------------------
__global__ __launch_bounds__(256) void k_xproj(
    const float* __restrict__ emb,
    const float* __restrict__ Wih_f, const float* __restrict__ b_f,
    const float* __restrict__ Wih_b, const float* __restrict__ b_b,
    const int*   __restrict__ sent,
    float* __restrict__ xp)
{
    __shared__ float As[16][68];
    __shared__ float Bs[16][68];
    __shared__ int   words[64];

    const int tid = threadIdx.x;
    const int n0  = blockIdx.x * 64;
    const int m0  = blockIdx.y * 64;
    const int dir = n0 >> 10;
    const int g0  = n0 & 1023;
    const float* __restrict__ Wih  = dir ? Wih_b : Wih_f;
    const float* __restrict__ bias = dir ? b_b   : b_f;

    if (tid < 64) words[tid] = sent[m0 + tid];
    __syncthreads();

    const int r = tid >> 2;
    const int q = tid & 3;
    const float* aptr = emb + (size_t)words[r] * EMB_ + q * 4;
    const float* bptr = Wih + (size_t)(g0 + r) * EMB_ + q * 4;

    const int tx = tid & 15;
    const int ty = tid >> 4;
    float acc[4][4] = {};

    for (int k0 = 0; k0 < 304; k0 += 16) {
        const int k = k0 + q * 4;
        float4 av = make_float4(0.f, 0.f, 0.f, 0.f);
        float4 bv = make_float4(0.f, 0.f, 0.f, 0.f);
        if (k < 300) {
            av = *(const float4*)(aptr + k0);
            bv = *(const float4*)(bptr + k0);
        }
        As[q*4+0][r] = av.x; As[q*4+1][r] = av.y; As[q*4+2][r] = av.z; As[q*4+3][r] = av.w;
        Bs[q*4+0][r] = bv.x; Bs[q*4+1][r] = bv.y; Bs[q*4+2][r] = bv.z; Bs[q*4+3][r] = bv.w;
        __syncthreads();
        #pragma unroll
        for (int kk = 0; kk < 16; ++kk) {
            const float4 a = *(const float4*)&As[kk][ty * 4];
            const float4 b = *(const float4*)&Bs[kk][tx * 4];
            acc[0][0] += a.x*b.x; acc[0][1] += a.x*b.y; acc[0][2] += a.x*b.z; acc[0][3] += a.x*b.w;
            acc[1][0] += a.y*b.x; acc[1][1] += a.y*b.y; acc[1][2] += a.y*b.z; acc[1][3] += a.y*b.w;
            acc[2][0] += a.z*b.x; acc[2][1] += a.z*b.y; acc[2][2] += a.z*b.z; acc[2][3] += a.z*b.w;
            acc[3][0] += a.w*b.x; acc[3][1] += a.w*b.y; acc[3][2] += a.w*b.z; acc[3][3] += a.w*b.w;
        }
        __syncthreads();
    }

    float* out = xp + (size_t)dir * M_ * G_;
    const int g = g0 + tx * 4;
    const float4 bs4 = *(const float4*)(bias + g);
    #pragma unroll
    for (int im = 0; im < 4; ++im) {
        const int m = m0 + ty * 4 + im;
        float4 rv;
        rv.x = acc[im][0] + bs4.x;
        rv.y = acc[im][1] + bs4.y;
        rv.z = acc[im][2] + bs4.z;
        rv.w = acc[im][3] + bs4.w;
        *(float4*)(out + (size_t)m * G_ + g) = rv;
    }
}

// ---------------------------------------------------------------------------
// Kernel 2: full bidirectional LSTM scan, one cooperative launch.
// 256 blocks = 32 clusters x 8 blocks. R6 restructure: wave owns 8 units x
// ALL 4 gates (lane = [u3|g|kh]); gate gather is an in-wave 4x4 shfl
// transpose, so activation runs per-wave on all 4 SIMDs and each wave
// PUBLISHES AS SOON AS ITS OWN GEMM IS DONE (no S2 gating on slowest wave).
// Cg LDS + cs LDS deleted (cell state in a register); hs double-buffered so
// ONE barrier per step is sufficient (S1: hs[t&1] writes vs reads; laggard
// waves read the other buffer, and S1(t-1) guards the t-2 reuse).
// Per-thread arithmetic order identical to R5 -> bitwise-identical output.
// ---------------------------------------------------------------------------
__global__ __launch_bounds__(256, 1) void k_lstm_scan(
    const float* __restrict__ Whh_f, const float* __restrict__ Whh_b,
    const float* __restrict__ xp, float* __restrict__ hbuf,
    u64* __restrict__ xch)
{
    const int rank = blockIdx.x & 7;        // block within cluster
    const int cl   = blockIdx.x >> 3;       // 0..31
    const int dir  = cl >> 4;
    const int bg   = cl & 15;
    const int b0   = bg * BPC;
    const int u0   = rank * UPB;
    const int tid  = threadIdx.x;
    const int lane = tid & 63;
    const int w    = tid >> 6;              // wave 0..3
    const int kh   = lane & 1;              // k-half (128 k each)
    const int gb0  = (lane >> 1) & 1;
    const int gb1  = (lane >> 2) & 1;
    const int g    = (lane >> 1) & 3;       // gate coord; batch coord post-transpose
    const int u_loc = (w << 3) | (lane >> 3);  // unit 0..31 within block

    const float* __restrict__ Whh = dir ? Whh_b : Whh_f;
    const float* __restrict__ xpd = xp + (size_t)dir * M_ * G_;
    float* __restrict__ hdir = hbuf + (size_t)dir * M_ * HID_;
    u64* __restrict__ xc = xch + ((size_t)dir * B_ + b0) * HID_;  // cluster slice

    __shared__ float hs[2][BPC][264];    // double-buffered h; k-halves at stride 132

    for (int i = tid; i < BPC * 264; i += 256) ((float*)hs[0])[i] = 0.f;

    // register-resident Whh slice: row (g*256 + u0 + u_loc), k in [128kh,128kh+128)
    f32x4 wv[32];
    {
        const f32x4* wrow = (const f32x4*)(Whh + (size_t)(g * HID_ + u0 + u_loc) * HID_ + kh * 128);
        #pragma unroll
        for (int i = 0; i < 32; ++i) wv[i] = wrow[i];
    }
    __syncthreads();

    float c_reg = 0.f;                   // cell state lives in a register now
    const int act = (kh == 0);

    for (int t = 0; t < T_; ++t) {
        const int t_eff = dir ? (T_ - 1 - t) : t;

        // force the weight VGPRs live at loop top (loads cannot sink)
        #pragma unroll
        for (int i = 0; i < 32; ++i) asm volatile("" : "+v"(wv[i]));

        // xp prefetch first: its latency overlaps the poll below
        float x0 = 0.f, x1 = 0.f, x2 = 0.f, x3 = 0.f;
        if (act) {
            const float* xrow = xpd + ((size_t)t_eff * B_ + (b0 + g)) * G_ + (u0 + u_loc);
            x0 = xrow[0]; x1 = xrow[HID_]; x2 = xrow[2 * HID_]; x3 = xrow[3 * HID_];
        }

        if (t > 0) {
            // poll the packed h words until their epoch tag == t
            // (word for (i,tid) is xc[i*256 + tid]: pb==i, pk==tid)
            const unsigned want = (unsigned)t;
            u64 v[4];
            #pragma unroll
            for (int i = 0; i < 4; ++i)
                v[i] = __hip_atomic_load(&xc[(size_t)i * HID_ + tid],
                                         __ATOMIC_RELAXED, __HIP_MEMORY_SCOPE_AGENT);
            while ((unsigned)(v[0] >> 32) != want || (unsigned)(v[1] >> 32) != want ||
                   (unsigned)(v[2] >> 32) != want || (unsigned)(v[3] >> 32) != want) {
                #pragma unroll
                for (int i = 0; i < 4; ++i)
                    if ((unsigned)(v[i] >> 32) != want)
                        v[i] = __hip_atomic_load(&xc[(size_t)i * HID_ + tid],
                                                 __ATOMIC_RELAXED, __HIP_MEMORY_SCOPE_AGENT);
            }
            float* hw = (float*)hs[t & 1];
            #pragma unroll
            for (int i = 0; i < 4; ++i)
                hw[i * 264 + ((tid >> 7) * 132) + (tid & 127)] =
                    __uint_as_float((unsigned)v[i]);
        }
        __syncthreads();   // S1: hs[t&1] ready (sole barrier per step)

        // gate GEMM: a[b] = sum_k Whh[g*256+u0+u_loc][k] * h_prev[b][k]
        // (identical per-thread summation order to R5: 32x dot4, then one
        //  shfl-add across the two k-halves)
        float a[4];
        #pragma unroll
        for (int b = 0; b < BPC; ++b) {
            const f32x4* hv = (const f32x4*)((const float*)hs[t & 1] + b * 264 + kh * 132);
            float acc = 0.f;
            #pragma unroll
            for (int i = 0; i < 32; ++i) {
                const f32x4 w4 = wv[i];
                const f32x4 h4 = hv[i];
                acc += w4.x * h4.x + w4.y * h4.y + w4.z * h4.z + w4.w * h4.w;
            }
            acc += __shfl_xor(acc, 1);
            a[b] = acc;
        }

        // in-wave 4x4 transpose: lane-bits 1,2 (gate) <-> reg index (batch).
        // After this, lane with coord G holds p0..p3 = gates i,f,g,o for batch G.
        // stage 1: lane-bit1 <-> reg-bit0
        const float s01 = gb0 ? a[0] : a[1];
        const float r01 = __shfl_xor(s01, 2);
        const float n0 = gb0 ? r01 : a[0];
        const float n1 = gb0 ? a[1] : r01;
        const float s23 = gb0 ? a[2] : a[3];
        const float r23 = __shfl_xor(s23, 2);
        const float n2 = gb0 ? r23 : a[2];
        const float n3 = gb0 ? a[3] : r23;
        // stage 2: lane-bit2 <-> reg-bit1
        const float s02 = gb1 ? n0 : n2;
        const float r02 = __shfl_xor(s02, 4);
        const float p0 = gb1 ? r02 : n0;
        const float p2 = gb1 ? n2 : r02;
        const float s13 = gb1 ? n1 : n3;
        const float r13 = __shfl_xor(s13, 4);
        const float p1 = gb1 ? r13 : n1;
        const float p3 = gb1 ? n3 : r13;

        if (act) {
            const float gi = p0 + x0;
            const float gf = p1 + x1;
            const float gg = p2 + x2;
            const float go = p3 + x3;
            const float i_ = 1.f / (1.f + __expf(-gi));
            const float f_ = 1.f / (1.f + __expf(-gf));
            const float g_ = tanhf(gg);
            const float o_ = 1.f / (1.f + __expf(-go));
            const float cn = f_ * c_reg + i_ * g_;
            const float hn = o_ * tanhf(cn);
            c_reg = cn;
            // publish packed (tag|h) for peers FIRST (critical path), then history
            if (t + 1 < T_) {
                const u64 pkv = ((u64)(unsigned)(t + 1) << 32) | __float_as_uint(hn);
                __hip_atomic_store(&xc[(size_t)g * HID_ + (u0 + u_loc)], pkv,
                                   __ATOMIC_RELAXED, __HIP_MEMORY_SCOPE_AGENT);
            }
            hdir[((size_t)t_eff * B_ + (b0 + g)) * HID_ + (u0 + u_loc)] = hn;
        }
        // no trailing barrier: next step's writes hit the other hs buffer,
        // and S1(t) already proved all waves are past their hs[t&1^1] reads.
    }
}

// ---------------------------------------------------------------------------
// Kernel 3: emissions[t,b,l] = b_top[l] + h_f . W_top[l,:256] + h_b . W_top[l,256:]
// ---------------------------------------------------------------------------
__global__ __launch_bounds__(256) void k_emis(
    const float* __restrict__ Wt, const float* __restrict__ bt,
    const float* __restrict__ hbuf, float* __restrict__ em)
{
    const int gid = blockIdx.x * 256 + threadIdx.x;
    if (gid >= M_ * L_) return;
    const int m = gid / L_;
    const int l = gid - m * L_;
    const float4* hf  = (const float4*)(hbuf + (size_t)m * HID_);
    const float4* hbk = (const float4*)(hbuf + (size_t)M_ * HID_ + (size_t)m * HID_);
    const float4* w0  = (const float4*)(Wt + (size_t)l * 2 * HID_);
    const float4* w1  = w0 + HID_ / 4;
    float acc = bt[l];
    #pragma unroll 4
    for (int k = 0; k < HID_ / 4; ++k) {
        float4 h = hf[k],  w = w0[k];
        acc += h.x*w.x + h.y*w.y + h.z*w.z + h.w*w.w;
        h = hbk[k]; w = w1[k];
        acc += h.x*w.x + h.y*w.y + h.z*w.z + h.w*w.w;
    }
    em[gid] = acc;
}

// ---------------------------------------------------------------------------
// Kernel 4: CRF per-sequence forward + gold score. One block per b.
// ---------------------------------------------------------------------------
__global__ __launch_bounds__(64) void k_crf(
    const float* __restrict__ start_t, const float* __restrict__ end_t,
    const float* __restrict__ trans,
    const int* __restrict__ sent, const int* __restrict__ labels,
    const float* __restrict__ em, float* __restrict__ res)
{
    const int b = blockIdx.x;
    const int tid = threadIdx.x;
    __shared__ float tr[L_ * L_];
    __shared__ float alpha[2][L_];
    __shared__ float red[64];
    __shared__ int   redi[64];
    __shared__ float sdenom;

    for (int i = tid; i < L_ * L_; i += 64) tr[i] = trans[i];
    if (tid < L_) alpha[0][tid] = start_t[tid] + em[b * L_ + tid];
    __syncthreads();

    float pre_em = (tid < L_) ? em[(B_ + b) * L_ + tid] : 0.f;
    int   pre_m  = sent[B_ + b];

    int p = 0;
    for (int t = 1; t < T_; ++t) {
        const float emt = pre_em;
        const int   mt  = pre_m;
        if (t + 1 < T_) {
            if (tid < L_) pre_em = em[((t + 1) * B_ + b) * L_ + tid];
            pre_m = sent[(t + 1) * B_ + b];
        }
        float val = 0.f;
        if (tid < L_) {
            if (mt != 0) {
                float mx = -1e30f;
                #pragma unroll
                for (int i = 0; i < L_; ++i) mx = fmaxf(mx, alpha[p][i] + tr[i * L_ + tid]);
                float s = 0.f;
                #pragma unroll
                for (int i = 0; i < L_; ++i) s += __expf(alpha[p][i] + tr[i * L_ + tid] - mx);
                val = mx + __logf(s) + emt;
            } else {
                val = alpha[p][tid];
            }
        }
        if (tid < L_) alpha[1 - p][tid] = val;
        __syncthreads();
        p ^= 1;
    }

    if (tid == 0) {
        float mx = -1e30f;
        for (int j = 0; j < L_; ++j) mx = fmaxf(mx, alpha[p][j] + end_t[j]);
        float s = 0.f;
        for (int j = 0; j < L_; ++j) s += __expf(alpha[p][j] + end_t[j] - mx);
        sdenom = mx + __logf(s);
    }

    float loc = 0.f;
    int   cnt = 0;
    for (int t = tid; t < T_; t += 64) {
        const int masked = (sent[t * B_ + b] != 0);
        cnt += masked;
        if (t >= 1 && masked) {
            const int tp = labels[(t - 1) * B_ + b];
            const int tc = labels[t * B_ + b];
            loc += tr[tp * L_ + tc] + em[(t * B_ + b) * L_ + tc];
        }
    }
    red[tid] = loc; redi[tid] = cnt;
    __syncthreads();
    if (tid == 0) {
        float s = 0.f; int c = 0;
        for (int i = 0; i < 64; ++i) { s += red[i]; c += redi[i]; }
        const int tag0 = labels[b];
        const int seq_end = c - 1;
        const int last = labels[seq_end * B_ + b];
        const float score = start_t[tag0] + em[b * L_ + tag0] + s + end_t[last];
        res[b] = score - sdenom;
    }
}

// ---------------------------------------------------------------------------
// Kernel 5: out[0] = -sum_b res[b]
// ---------------------------------------------------------------------------
__global__ __launch_bounds__(64) void k_final(const float* __restrict__ res,
                                              float* __restrict__ out)
{
    __shared__ float red[64];
    red[threadIdx.x] = res[threadIdx.x];
    __syncthreads();
    if (threadIdx.x == 0) {
        float s = 0.f;
        for (int i = 0; i < 64; ++i) s += red[i];
        out[0] = -s;
    }
}

// ---------------------------------------------------------------------------
extern "C" void kernel_launch(void* const* d_in, const int* in_sizes, int n_in,
                              void* d_out, int out_size, void* d_ws, size_t ws_size,
                              hipStream_t stream)
{
    const float* emb     = (const float*)d_in[0];
    const float* Wih_f   = (const float*)d_in[1];
    const float* Whh_f   = (const float*)d_in[2];
    const float* b_f     = (const float*)d_in[3];
    const float* Wih_b   = (const float*)d_in[4];
    const float* Whh_b   = (const float*)d_in[5];
    const float* b_b     = (const float*)d_in[6];
    const float* W_top   = (const float*)d_in[7];
    const float* b_top   = (const float*)d_in[8];
    const float* start_t = (const float*)d_in[9];
    const float* end_t   = (const float*)d_in[10];
    const float* trans   = (const float*)d_in[11];
    const int*   sent    = (const int*)d_in[12];
    const int*   labels  = (const int*)d_in[13];
    float* out = (float*)d_out;

    float* wsf  = (float*)d_ws;
    float* xp   = wsf;                                   // 2*M*G floats
    float* hbuf = xp   + (size_t)2 * M_ * G_;            // 2*M*H
    float* em   = hbuf + (size_t)2 * M_ * HID_;          // M*L
    float* res  = em   + (size_t)M_ * L_;                // B
    u64*   xch  = (u64*)(res + 64);                      // 2*B*H packed words

    // 1) input projection GEMM (both dirs)
    k_xproj<<<dim3(2048 / 64, M_ / 64), 256, 0, stream>>>(
        emb, Wih_f, b_f, Wih_b, b_b, sent, xp);

    // 2) whole bidirectional scan, one cooperative launch
    //    (xch needs NO init: tags are 1..255, ws poison 0xAA never matches)
    {
        void* args[] = { (void*)&Whh_f, (void*)&Whh_b, (void*)&xp, (void*)&hbuf, (void*)&xch };
        hipLaunchCooperativeKernel((const void*)k_lstm_scan, dim3(256), dim3(256),
                                   args, 0, stream);
    }

    // 3) emissions
    k_emis<<<(M_ * L_ + 255) / 256, 256, 0, stream>>>(W_top, b_top, hbuf, em);

    // 4) CRF per-sequence
    k_crf<<<B_, 64, 0, stream>>>(start_t, end_t, trans, sent, labels, em, res);

    // 5) final sum
    k_final<<<1, 64, 0, stream>>>(res, out);
}